// Round 7
// baseline (307.536 us; speedup 1.0000x reference)
//
#include <hip/hip_runtime.h>

#define T_LEN 512
#define NHID 16
#define NEMB 10
#define VOCAB1 50001
#define ISTR 524   // idx row stride (ints): covers t+7 prefetch, 12 mod 32 -> 2-way reads (free)

typedef float v2f __attribute__((ext_vector_type(2)));
typedef float v4f __attribute__((ext_vector_type(4)));
typedef _Float16 v4h __attribute__((ext_vector_type(4)));

// ---------------------------------------------------------------------------
// Kernel 1: xproj table, ROW-MAJOR: tbl[v*64 + r] = bih[r]+bhh[r] + emb[v]·Wih[r]
// (r = gate-major row: i=0..15, f=16..31, g=32..47, o=48..63).
// MFMA C-fragment for lane (p,n), chunk q = float4 at tbl4[v*16 + q*4 + p].
// ---------------------------------------------------------------------------
__global__ __launch_bounds__(256) void build_table_r(
    const float* __restrict__ emb, const float* __restrict__ Wih,
    const float* __restrict__ bih, const float* __restrict__ bhh,
    float* __restrict__ tbl)
{
    const int tid = blockIdx.x * 256 + threadIdx.x;
    if (tid >= VOCAB1 * 64) return;
    const int v = tid >> 6, r = tid & 63;
    float a = bih[r] + bhh[r];
    #pragma unroll
    for (int e = 0; e < NEMB; ++e) a += emb[v * NEMB + e] * Wih[r * NEMB + e];
    tbl[tid] = a;   // coalesced
}

// ---------------------------------------------------------------------------
// Kernel 2: MFMA recurrence. 1 wave = 16 batches, 256 blocks (1 wave/CU).
// v_mfma_f32_16x16x16f16 layouts (AMD matrix-core mapping, C/D verified m89):
//   A[m][k]: lane l holds A[l&15][4*(l>>4)+j]   (Whh chunk q, loaded once)
//   B[k][n]: lane l holds B[4*(l>>4)+j][l&15]   (h in f16 — lane-local!)
//   D[m][n]: lane l holds D[4*(l>>4)+j][l&15]
// => lane (p,n) gets gates i,f,g,o for units 4p..4p+3 of batch n; the next
// step's B-fragment is exactly the h values it just computed. No exchange.
// xproj enters as the MFMA C operand (4 float4 loads/step, 4-deep pipeline).
// ---------------------------------------------------------------------------
__global__ __launch_bounds__(64) void lstm_mfma_kernel(
    const int*   __restrict__ x,
    const float* __restrict__ tbl,
    const float* __restrict__ Whh,
    const float* __restrict__ Wfc,
    const float* __restrict__ bfc,
    float*       __restrict__ out)
{
    __shared__ int idxs[16 * ISTR];   // [batch][t] token*16 (float4-row index), 33.5 KB

    const int l = threadIdx.x;        // 0..63
    const int n = l & 15;             // batch within group
    const int p = l >> 4;             // unit-block 0..3 (owns units 4p..4p+3)
    const int base = blockIdx.x * 16;

    // stage tokens, pre-scaled to float4-row index (v*16). t>=T_LEN -> 0.
    #pragma unroll 1
    for (int b = 0; b < 16; ++b) {
        const int* xr = x + (long)(base + b) * T_LEN;
        for (int t = l; t < ISTR; t += 64)
            idxs[b * ISTR + t] = (t < T_LEN) ? (xr[t] << 4) : 0;
    }
    __syncthreads();   // single wave; cheap

    // A-fragments: Whh chunk q (rows q*16..q*16+15), lane holds row l&15, k=4p+j
    v4h wA[4];
    #pragma unroll
    for (int q = 0; q < 4; ++q) {
        const int r = q * 16 + n;
        #pragma unroll
        for (int j = 0; j < 4; ++j)
            wA[q][j] = (_Float16)Whh[r * NHID + 4 * p + j];
    }

    float h[4] = {0.f, 0.f, 0.f, 0.f};
    float c[4] = {0.f, 0.f, 0.f, 0.f};

    const float NL2E  = -1.44269504088896f;
    const float NL2E2 = -2.88539008177793f;
    const v4f* t4 = (const v4f*)tbl;
    const int* myidx = &idxs[n * ISTR];

    // 4-deep compile-time-indexed pipeline of C-fragments (16 loads in flight)
    v4f pf[4][4];
    #pragma unroll
    for (int s = 0; s < 4; ++s) {
        const int iv = myidx[s] + p;
        #pragma unroll
        for (int q = 0; q < 4; ++q) pf[s][q] = t4[iv + q * 4];
    }

    #pragma unroll 1
    for (int t = 0; t < T_LEN; t += 4) {
        #pragma unroll
        for (int u = 0; u < 4; ++u) {
            // B-fragment: this lane's own h, converted to f16
            v4h hb;
            #pragma unroll
            for (int j = 0; j < 4; ++j) hb[j] = (_Float16)h[j];

            // gates = Whh·h + xproj  (one MFMA per gate chunk, C = xproj)
            const v4f d0 = __builtin_amdgcn_mfma_f32_16x16x16f16(wA[0], hb, pf[u][0], 0, 0, 0);
            const v4f d1 = __builtin_amdgcn_mfma_f32_16x16x16f16(wA[1], hb, pf[u][1], 0, 0, 0);
            const v4f d2 = __builtin_amdgcn_mfma_f32_16x16x16f16(wA[2], hb, pf[u][2], 0, 0, 0);
            const v4f d3 = __builtin_amdgcn_mfma_f32_16x16x16f16(wA[3], hb, pf[u][3], 0, 0, 0);

            // refill stage u with step t+4+u (stays in flight 4 steps)
            {
                const int iv = myidx[t + 4 + u] + p;
                #pragma unroll
                for (int q = 0; q < 4; ++q) pf[u][q] = t4[iv + q * 4];
            }

            // lane-local nonlinearities + state update (units 4p..4p+3, batch n)
            #pragma unroll
            for (int j = 0; j < 4; ++j) {
                const float ig = __builtin_amdgcn_rcpf(1.f + __builtin_amdgcn_exp2f(d0[j] * NL2E));
                const float fg = __builtin_amdgcn_rcpf(1.f + __builtin_amdgcn_exp2f(d1[j] * NL2E));
                const float gg = 2.f * __builtin_amdgcn_rcpf(1.f + __builtin_amdgcn_exp2f(d2[j] * NL2E2)) - 1.f;
                const float og = __builtin_amdgcn_rcpf(1.f + __builtin_amdgcn_exp2f(d3[j] * NL2E));
                c[j] = fg * c[j] + ig * gg;
                const float tc = 2.f * __builtin_amdgcn_rcpf(1.f + __builtin_amdgcn_exp2f(c[j] * NL2E2)) - 1.f;
                h[j] = og * tc;
            }
        }
    }

    // logit: partial dot over this lane's 4 units, reduce across p (xor 16,32)
    float s = 0.f;
    #pragma unroll
    for (int j = 0; j < 4; ++j) s += h[j] * Wfc[4 * p + j];
    s += __shfl_xor(s, 16, 64);
    s += __shfl_xor(s, 32, 64);
    if (p == 0)
        out[base + n] = __builtin_amdgcn_rcpf(1.f + __builtin_amdgcn_exp2f((s + bfc[0]) * NL2E));
}

// ---------------------------------------------------------------------------
// Fallback (ws too small for the 12.8 MB table): R5's on-the-fly fp32 path.
// ---------------------------------------------------------------------------
__global__ __launch_bounds__(256) void lstm_fb_kernel(
    const int*   __restrict__ x,
    const float* __restrict__ emb,
    const float* __restrict__ Wih,
    const float* __restrict__ Whh,
    const float* __restrict__ bih,
    const float* __restrict__ bhh,
    const float* __restrict__ Wfc,
    const float* __restrict__ bfc,
    float*       __restrict__ out)
{
    __shared__ int   idx_lds[T_LEN][17];
    __shared__ float hx[16][20];

    const int tid  = threadIdx.x;
    const int lane = tid & 63;
    const int j    = lane & 15;
    const int lb   = tid >> 4;
    const int batch = blockIdx.x * 16 + lb;

    for (int i = tid; i < 16 * T_LEN; i += 256) {
        const int b = i & 15;
        const int t = i >> 4;
        idx_lds[t][b] = x[(blockIdx.x * 16 + b) * T_LEN + t];
    }

    float wih[4][NEMB], bias[4];
    v2f w[4][8];
    #pragma unroll
    for (int q = 0; q < 4; ++q) {
        const int r = j + 16 * q;
        #pragma unroll
        for (int e = 0; e < NEMB; ++e) wih[q][e] = Wih[r * NEMB + e];
        #pragma unroll
        for (int p = 0; p < 8; ++p)
            w[q][p] = (v2f){Whh[r * NHID + 2 * p], Whh[r * NHID + 2 * p + 1]};
        bias[q] = bih[r] + bhh[r];
    }

    __syncthreads();

    v2f h2[8];
    #pragma unroll
    for (int p = 0; p < 8; ++p) h2[p] = (v2f){0.f, 0.f};
    float c = 0.f;

    const float NL2E  = -1.44269504088896f;
    const float NL2E2 = -2.88539008177793f;
    const float4* hp = (const float4*)&hx[lb][0];

    float2 xa, xb, xc, xd, xe2;
    {
        const float2* er = (const float2*)(emb + (long)idx_lds[0][lb] * NEMB);
        xa = er[0]; xb = er[1]; xc = er[2]; xd = er[3]; xe2 = er[4];
    }
    int idx_n = idx_lds[1][lb];

    #pragma unroll 1
    for (int t = 0; t < T_LEN; ++t) {
        const float xv[NEMB] = {xa.x, xa.y, xb.x, xb.y, xc.x, xc.y,
                                xd.x, xd.y, xe2.x, xe2.y};
        if (t + 1 < T_LEN) {
            const float2* er = (const float2*)(emb + (long)idx_n * NEMB);
            xa = er[0]; xb = er[1]; xc = er[2]; xd = er[3]; xe2 = er[4];
        }
        const int idx_nn = (t + 2 < T_LEN) ? idx_lds[t + 2][lb] : 0;

        float v[4];
        #pragma unroll
        for (int q = 0; q < 4; ++q) {
            float a = bias[q];
            #pragma unroll
            for (int e = 0; e < NEMB; ++e) a += xv[e] * wih[q][e];
            v[q] = a;
        }
        v2f a0 = (v2f){v[0], 0.f}, a1 = (v2f){v[1], 0.f};
        v2f a2 = (v2f){v[2], 0.f}, a3 = (v2f){v[3], 0.f};
        #pragma unroll
        for (int p = 0; p < 8; ++p) {
            a0 += h2[p] * w[0][p];
            a1 += h2[p] * w[1][p];
            a2 += h2[p] * w[2][p];
            a3 += h2[p] * w[3][p];
        }
        const float vi = a0.x + a0.y, vf = a1.x + a1.y;
        const float vg = a2.x + a2.y, vo = a3.x + a3.y;

        const float ig = __builtin_amdgcn_rcpf(1.f + __builtin_amdgcn_exp2f(vi * NL2E));
        const float fg = __builtin_amdgcn_rcpf(1.f + __builtin_amdgcn_exp2f(vf * NL2E));
        const float gg = 2.f * __builtin_amdgcn_rcpf(1.f + __builtin_amdgcn_exp2f(vg * NL2E2)) - 1.f;
        const float og = __builtin_amdgcn_rcpf(1.f + __builtin_amdgcn_exp2f(vo * NL2E));

        c = fg * c + ig * gg;
        const float tc = 2.f * __builtin_amdgcn_rcpf(1.f + __builtin_amdgcn_exp2f(c * NL2E2)) - 1.f;
        const float hv = og * tc;

        hx[lb][j] = hv;
        const float4 b0 = hp[0], b1 = hp[1], b2 = hp[2], b3 = hp[3];
        h2[0] = (v2f){b0.x, b0.y}; h2[1] = (v2f){b0.z, b0.w};
        h2[2] = (v2f){b1.x, b1.y}; h2[3] = (v2f){b1.z, b1.w};
        h2[4] = (v2f){b2.x, b2.y}; h2[5] = (v2f){b2.z, b2.w};
        h2[6] = (v2f){b3.x, b3.y}; h2[7] = (v2f){b3.z, b3.w};

        idx_n = idx_nn;
    }

    if (j == 0) {
        float logit = bfc[0];
        #pragma unroll
        for (int p = 0; p < 8; ++p)
            logit += h2[p].x * Wfc[2 * p] + h2[p].y * Wfc[2 * p + 1];
        out[batch] = __builtin_amdgcn_rcpf(1.f + __builtin_amdgcn_exp2f(logit * NL2E));
    }
}

extern "C" void kernel_launch(void* const* d_in, const int* in_sizes, int n_in,
                              void* d_out, int out_size, void* d_ws, size_t ws_size,
                              hipStream_t stream) {
    const int*   x   = (const int*)  d_in[0];
    const float* emb = (const float*)d_in[1];
    const float* Wih = (const float*)d_in[2];
    const float* Whh = (const float*)d_in[3];
    const float* bih = (const float*)d_in[4];
    const float* bhh = (const float*)d_in[5];
    const float* Wfc = (const float*)d_in[6];
    const float* bfc = (const float*)d_in[7];
    float* outp = (float*)d_out;

    const int B = in_sizes[0] / T_LEN;                               // 4096
    const size_t TABLE_BYTES = (size_t)VOCAB1 * 64 * sizeof(float);  // 12.8 MB

    if (ws_size >= TABLE_BYTES) {
        float* tbl = (float*)d_ws;
        build_table_r<<<(VOCAB1 * 64 + 255) / 256, 256, 0, stream>>>(emb, Wih, bih, bhh, tbl);
        lstm_mfma_kernel<<<B / 16, 64, 0, stream>>>(x, tbl, Whh, Wfc, bfc, outp);
    } else {
        lstm_fb_kernel<<<B / 16, 256, 0, stream>>>(x, emb, Wih, Whh, bih, bhh, Wfc, bfc, outp);
    }
}

// Round 8
// 180.069 us; speedup vs baseline: 1.7079x; 1.7079x over previous
//
#include <hip/hip_runtime.h>

#define T_LEN 512
#define NHID 16
#define NEMB 10
#define VOCAB1 50001
#define IROW 520   // idx row length (ints): covers t+7 prefetch; 520%32=8 -> 4 groups hit 4 banks

typedef float v2f __attribute__((ext_vector_type(2)));

// ---------------------------------------------------------------------------
// Kernel 1: xproj table, layout [v][16][4] f32: float4 at (v*16+j) =
//   {i,f,g,o} pre-activations for unit j = bih+bhh + emb[v]·Wih rows. (R5)
// ---------------------------------------------------------------------------
__global__ __launch_bounds__(256) void build_table(
    const float* __restrict__ emb, const float* __restrict__ Wih,
    const float* __restrict__ bih, const float* __restrict__ bhh,
    float* __restrict__ tbl)
{
    const int tid = blockIdx.x * 256 + threadIdx.x;
    if (tid >= VOCAB1 * 16) return;
    const int v = tid >> 4, j = tid & 15;
    float e[NEMB];
    #pragma unroll
    for (int i = 0; i < NEMB; ++i) e[i] = emb[v * NEMB + i];
    float o[4];
    #pragma unroll
    for (int q = 0; q < 4; ++q) {
        const int r = q * 16 + j;
        float a = bih[r] + bhh[r];
        #pragma unroll
        for (int i = 0; i < NEMB; ++i) a += e[i] * Wih[r * NEMB + i];
        o[q] = a;
    }
    ((float4*)tbl)[tid] = make_float4(o[0], o[1], o[2], o[3]);
}

// ROW_ROR:r within 16-lane DPP row: D[l] = S[(l-r)&15]  (shfl_up convention)
#define DPP_ROR(dst, src_i, r)                                                   \
    dst = __builtin_bit_cast(float, __builtin_amdgcn_update_dpp(                 \
              0, src_i, 0x120 + r, 0xF, 0xF, true))

// ---------------------------------------------------------------------------
// Kernel 2: R5 structure (16 lanes/batch, 4 batch/wave, 1024 waves, 4-deep
// compile-time-indexed table pipeline) with the LDS h-exchange replaced by
// in-register DPP row-rotation broadcast: hr[r] = h[(j-r)&15], weights
// pre-permuted per lane so gate_q = xproj_q + sum_r hr[r]*w[q][r]. No LDS
// in the recurrence at all; exact fp32 math.
// ---------------------------------------------------------------------------
__global__ __launch_bounds__(256) void lstm_dpp_kernel(
    const int*   __restrict__ x,
    const float* __restrict__ tbl,
    const float* __restrict__ Whh,
    const float* __restrict__ Wfc,
    const float* __restrict__ bfc,
    float*       __restrict__ out)
{
    __shared__ int idxs[16][IROW];   // [batch][t] token*16, 33.3 KB

    const int tid = threadIdx.x;
    const int j   = tid & 15;        // hidden unit owned
    const int lb  = tid >> 4;        // local batch 0..15
    const int batch = blockIdx.x * 16 + lb;

    // stage tokens, pre-scaled to float4-row index. Coalesced reads,
    // conflict-free writes (consecutive tid -> consecutive banks).
    #pragma unroll 1
    for (int b = 0; b < 16; ++b) {
        const int* xr = x + (size_t)(blockIdx.x * 16 + b) * T_LEN;
        for (int t = tid; t < IROW; t += 256)
            idxs[b][t] = (t < T_LEN) ? (xr[t] << 4) : 0;
    }
    __syncthreads();

    // per-lane permuted recurrent weights: w[q][r] = Whh[q*16+j][(j-r)&15]
    float w[4][16];
    #pragma unroll
    for (int q = 0; q < 4; ++q) {
        const int row = (q * 16 + j) * NHID;
        #pragma unroll
        for (int r = 0; r < 16; ++r)
            w[q][r] = Whh[row + ((j - r) & 15)];
    }

    float h = 0.f, c = 0.f;
    const float NL2E  = -1.44269504088896f;
    const float NL2E2 = -2.88539008177793f;
    const float4* t4 = (const float4*)tbl;

    // 4-deep pipeline of table rows (compile-time stage indices; counted vmcnt)
    float4 pf[4];
    #pragma unroll
    for (int s = 0; s < 4; ++s)
        pf[s] = t4[idxs[lb][s] + j];

    #pragma unroll 1
    for (int t = 0; t < T_LEN; t += 4) {
        #pragma unroll
        for (int u = 0; u < 4; ++u) {
            const float4 tb = pf[u];
            pf[u] = t4[idxs[lb][t + 4 + u] + j];   // stays in flight 4 steps

            // broadcast h across the 16-lane group via DPP row rotations
            float hr[16];
            const int hvi = __builtin_bit_cast(int, h);
            hr[0] = h;
            DPP_ROR(hr[1],  hvi, 1);   DPP_ROR(hr[2],  hvi, 2);
            DPP_ROR(hr[3],  hvi, 3);   DPP_ROR(hr[4],  hvi, 4);
            DPP_ROR(hr[5],  hvi, 5);   DPP_ROR(hr[6],  hvi, 6);
            DPP_ROR(hr[7],  hvi, 7);   DPP_ROR(hr[8],  hvi, 8);
            DPP_ROR(hr[9],  hvi, 9);   DPP_ROR(hr[10], hvi, 10);
            DPP_ROR(hr[11], hvi, 11);  DPP_ROR(hr[12], hvi, 12);
            DPP_ROR(hr[13], hvi, 13);  DPP_ROR(hr[14], hvi, 14);
            DPP_ROR(hr[15], hvi, 15);

            // gate pre-activations (bias + x-proj folded into tb)
            float a0 = tb.x, a1 = tb.y, a2 = tb.z, a3 = tb.w;
            #pragma unroll
            for (int r = 0; r < 16; ++r) {
                a0 = fmaf(hr[r], w[0][r], a0);
                a1 = fmaf(hr[r], w[1][r], a1);
                a2 = fmaf(hr[r], w[2][r], a2);
                a3 = fmaf(hr[r], w[3][r], a3);
            }

            const float ig = __builtin_amdgcn_rcpf(1.f + __builtin_amdgcn_exp2f(a0 * NL2E));
            const float fg = __builtin_amdgcn_rcpf(1.f + __builtin_amdgcn_exp2f(a1 * NL2E));
            const float gg = 2.f * __builtin_amdgcn_rcpf(1.f + __builtin_amdgcn_exp2f(a2 * NL2E2)) - 1.f;
            const float og = __builtin_amdgcn_rcpf(1.f + __builtin_amdgcn_exp2f(a3 * NL2E));

            c = fg * c + ig * gg;
            const float tc = 2.f * __builtin_amdgcn_rcpf(1.f + __builtin_amdgcn_exp2f(c * NL2E2)) - 1.f;
            h = og * tc;
        }
    }

    // logit: reduce h*Wfc over the 16-lane group (epilogue only, cheap)
    float s = h * Wfc[j];
    s += __shfl_xor(s, 1, 64);
    s += __shfl_xor(s, 2, 64);
    s += __shfl_xor(s, 4, 64);
    s += __shfl_xor(s, 8, 64);
    if (j == 0)
        out[batch] = __builtin_amdgcn_rcpf(1.f + __builtin_amdgcn_exp2f((s + bfc[0]) * NL2E));
}

// ---------------------------------------------------------------------------
// Fallback (ws too small for the 12.8 MB table): R5's on-the-fly fp32 path.
// ---------------------------------------------------------------------------
__global__ __launch_bounds__(256) void lstm_fb_kernel(
    const int*   __restrict__ x,
    const float* __restrict__ emb,
    const float* __restrict__ Wih,
    const float* __restrict__ Whh,
    const float* __restrict__ bih,
    const float* __restrict__ bhh,
    const float* __restrict__ Wfc,
    const float* __restrict__ bfc,
    float*       __restrict__ out)
{
    __shared__ int   idx_lds[T_LEN][17];
    __shared__ float hx[16][20];

    const int tid  = threadIdx.x;
    const int lane = tid & 63;
    const int j    = lane & 15;
    const int lb   = tid >> 4;
    const int batch = blockIdx.x * 16 + lb;

    for (int i = tid; i < 16 * T_LEN; i += 256) {
        const int b = i & 15;
        const int t = i >> 4;
        idx_lds[t][b] = x[(blockIdx.x * 16 + b) * T_LEN + t];
    }

    float wih[4][NEMB], bias[4];
    v2f w[4][8];
    #pragma unroll
    for (int q = 0; q < 4; ++q) {
        const int r = j + 16 * q;
        #pragma unroll
        for (int e = 0; e < NEMB; ++e) wih[q][e] = Wih[r * NEMB + e];
        #pragma unroll
        for (int p = 0; p < 8; ++p)
            w[q][p] = (v2f){Whh[r * NHID + 2 * p], Whh[r * NHID + 2 * p + 1]};
        bias[q] = bih[r] + bhh[r];
    }

    __syncthreads();

    v2f h2[8];
    #pragma unroll
    for (int p = 0; p < 8; ++p) h2[p] = (v2f){0.f, 0.f};
    float c = 0.f;

    const float NL2E  = -1.44269504088896f;
    const float NL2E2 = -2.88539008177793f;
    const float4* hp = (const float4*)&hx[lb][0];

    float2 xa, xb, xc, xd, xe2;
    {
        const float2* er = (const float2*)(emb + (long)idx_lds[0][lb] * NEMB);
        xa = er[0]; xb = er[1]; xc = er[2]; xd = er[3]; xe2 = er[4];
    }
    int idx_n = idx_lds[1][lb];

    #pragma unroll 1
    for (int t = 0; t < T_LEN; ++t) {
        const float xv[NEMB] = {xa.x, xa.y, xb.x, xb.y, xc.x, xc.y,
                                xd.x, xd.y, xe2.x, xe2.y};
        if (t + 1 < T_LEN) {
            const float2* er = (const float2*)(emb + (long)idx_n * NEMB);
            xa = er[0]; xb = er[1]; xc = er[2]; xd = er[3]; xe2 = er[4];
        }
        const int idx_nn = (t + 2 < T_LEN) ? idx_lds[t + 2][lb] : 0;

        float v[4];
        #pragma unroll
        for (int q = 0; q < 4; ++q) {
            float a = bias[q];
            #pragma unroll
            for (int e = 0; e < NEMB; ++e) a += xv[e] * wih[q][e];
            v[q] = a;
        }
        v2f a0 = (v2f){v[0], 0.f}, a1 = (v2f){v[1], 0.f};
        v2f a2 = (v2f){v[2], 0.f}, a3 = (v2f){v[3], 0.f};
        #pragma unroll
        for (int p = 0; p < 8; ++p) {
            a0 += h2[p] * w[0][p];
            a1 += h2[p] * w[1][p];
            a2 += h2[p] * w[2][p];
            a3 += h2[p] * w[3][p];
        }
        const float vi = a0.x + a0.y, vf = a1.x + a1.y;
        const float vg = a2.x + a2.y, vo = a3.x + a3.y;

        const float ig = __builtin_amdgcn_rcpf(1.f + __builtin_amdgcn_exp2f(vi * NL2E));
        const float fg = __builtin_amdgcn_rcpf(1.f + __builtin_amdgcn_exp2f(vf * NL2E));
        const float gg = 2.f * __builtin_amdgcn_rcpf(1.f + __builtin_amdgcn_exp2f(vg * NL2E2)) - 1.f;
        const float og = __builtin_amdgcn_rcpf(1.f + __builtin_amdgcn_exp2f(vo * NL2E));

        c = fg * c + ig * gg;
        const float tc = 2.f * __builtin_amdgcn_rcpf(1.f + __builtin_amdgcn_exp2f(c * NL2E2)) - 1.f;
        const float hv = og * tc;

        hx[lb][j] = hv;
        const float4 b0 = hp[0], b1 = hp[1], b2 = hp[2], b3 = hp[3];
        h2[0] = (v2f){b0.x, b0.y}; h2[1] = (v2f){b0.z, b0.w};
        h2[2] = (v2f){b1.x, b1.y}; h2[3] = (v2f){b1.z, b1.w};
        h2[4] = (v2f){b2.x, b2.y}; h2[5] = (v2f){b2.z, b2.w};
        h2[6] = (v2f){b3.x, b3.y}; h2[7] = (v2f){b3.z, b3.w};

        idx_n = idx_nn;
    }

    if (j == 0) {
        float logit = bfc[0];
        #pragma unroll
        for (int p = 0; p < 8; ++p)
            logit += h2[p].x * Wfc[2 * p] + h2[p].y * Wfc[2 * p + 1];
        out[batch] = __builtin_amdgcn_rcpf(1.f + __builtin_amdgcn_exp2f(logit * NL2E));
    }
}

extern "C" void kernel_launch(void* const* d_in, const int* in_sizes, int n_in,
                              void* d_out, int out_size, void* d_ws, size_t ws_size,
                              hipStream_t stream) {
    const int*   x   = (const int*)  d_in[0];
    const float* emb = (const float*)d_in[1];
    const float* Wih = (const float*)d_in[2];
    const float* Whh = (const float*)d_in[3];
    const float* bih = (const float*)d_in[4];
    const float* bhh = (const float*)d_in[5];
    const float* Wfc = (const float*)d_in[6];
    const float* bfc = (const float*)d_in[7];
    float* outp = (float*)d_out;

    const int B = in_sizes[0] / T_LEN;                               // 4096
    const size_t TABLE_BYTES = (size_t)VOCAB1 * 64 * sizeof(float);  // 12.8 MB

    if (ws_size >= TABLE_BYTES) {
        float* tbl = (float*)d_ws;
        build_table<<<(VOCAB1 * 16 + 255) / 256, 256, 0, stream>>>(emb, Wih, bih, bhh, tbl);
        lstm_dpp_kernel<<<B / 16, 256, 0, stream>>>(x, tbl, Whh, Wfc, bfc, outp);
    } else {
        lstm_fb_kernel<<<B / 16, 256, 0, stream>>>(x, emb, Wih, Whh, bih, bhh, Wfc, bfc, outp);
    }
}